// Round 6
// baseline (210.348 us; speedup 1.0000x reference)
//
#include <hip/hip_runtime.h>

#define Bn 4096
#define NF 20
#define NEMB 16
#define HIDN 512
#define KE 16
#define GIN 320
#define NKS 10   // K-steps of 32

typedef __attribute__((ext_vector_type(8))) short short8;
typedef __attribute__((ext_vector_type(4))) float f32x4;

__device__ __forceinline__ unsigned short f2bf(float f) {
  unsigned int u = __builtin_bit_cast(unsigned int, f);
  u += 0x7fff + ((u >> 16) & 1);
  return (unsigned short)(u >> 16);
}
__device__ __forceinline__ float bf2f(unsigned short h) {
  unsigned int u = ((unsigned int)h) << 16;
  return __builtin_bit_cast(float, u);
}

__device__ __forceinline__ void gload_lds16(const unsigned short* g, void* l) {
  __builtin_amdgcn_global_load_lds(
      (const __attribute__((address_space(1))) unsigned int*)g,
      (__attribute__((address_space(3))) unsigned int*)l, 16, 0, 0);
}

// counted vmcnt wait + scheduling fence (rule #18)
__device__ __forceinline__ void vwait(int n) {
  switch (n) {
#define C(N) case N: asm volatile("s_waitcnt vmcnt(" #N ")" ::: "memory"); break;
    C(0) C(1) C(2) C(3) C(4) C(5) C(6) C(7) C(8) C(9)
    C(10) C(11) C(12) C(13) C(14) C(15) C(16) C(17) C(18)
#undef C
    default: asm volatile("s_waitcnt vmcnt(0)" ::: "memory"); break;
  }
  __builtin_amdgcn_sched_barrier(0);
}

// ---------------- prep: gathers, bf16 conversion, fragment-ordered weights --
__global__ __launch_bounds__(256) void prep_kernel(
    const int* __restrict__ x, const int* __restrict__ sql,
    const float* __restrict__ demb, const float* __restrict__ semb,
    const float* __restrict__ gw1, const float* __restrict__ ew1,
    unsigned short* __restrict__ XE, unsigned short* __restrict__ SH,
    unsigned short* __restrict__ SL, unsigned short* __restrict__ GWF,
    unsigned short* __restrict__ EWF, float* __restrict__ y,
    int* __restrict__ cnt) {
  long long t = (long long)blockIdx.x * 256 + threadIdx.x;
  if (t < 81920) {
    int row = (int)(t / NF), f = (int)(t % NF);
    int idx = x[row * NF + f];
    const float* s = demb + (size_t)idx * NEMB;
    short8 o0, o1;
#pragma unroll
    for (int i = 0; i < 8; i++) {
      o0[i] = (short)f2bf(s[i]);
      o1[i] = (short)f2bf(s[8 + i]);
    }
    size_t o = (size_t)row * GIN + f * NEMB;
    *(short8*)(XE + o) = o0;
    *(short8*)(XE + o + 8) = o1;
    return;
  }
  t -= 81920;
  if (t < 81920) {
    int row = (int)(t / NF), f = (int)(t % NF);
    int idx = sql[row * NF + f];
    const float* s = semb + (size_t)idx * NEMB;
    short8 h0, h1, l0, l1;
#pragma unroll
    for (int i = 0; i < 8; i++) {
      float v = s[i];
      unsigned short hb = f2bf(v);
      h0[i] = (short)hb; l0[i] = (short)f2bf(v - bf2f(hb));
      v = s[8 + i];
      hb = f2bf(v);
      h1[i] = (short)hb; l1[i] = (short)f2bf(v - bf2f(hb));
    }
    size_t o = (size_t)row * GIN + f * NEMB;
    *(short8*)(SH + o) = h0; *(short8*)(SH + o + 8) = h1;
    *(short8*)(SL + o) = l0; *(short8*)(SL + o + 8) = l1;
    return;
  }
  t -= 81920;
  if (t < 40960) {
    int s = (int)(t / 20480), r = (int)(t % 20480);
    int ks = r / 2048, r2 = r % 2048, nt = r2 / 64, l = r2 % 64;
    int k0 = ks * 32 + (l >> 4) * 8, n = nt * 16 + (l & 15);
    short8 o;
#pragma unroll
    for (int j = 0; j < 8; j++) {
      float w = gw1[(size_t)(k0 + j) * HIDN + n];
      unsigned short hb = f2bf(w);
      o[j] = (s == 0) ? (short)hb : (short)f2bf(w - bf2f(hb));
    }
    *(short8*)(GWF + ((((size_t)s * NKS + ks) * 32 + nt) * 64 + l) * 8) = o;
    return;
  }
  t -= 40960;
  if (t < 327680) {
    int e = (int)(t / 20480), r = (int)(t % 20480);
    int ks = r / 2048, r2 = r % 2048, nt = r2 / 64, l = r2 % 64;
    int k0 = ks * 32 + (l >> 4) * 8, n = nt * 16 + (l & 15);
    const float* W = ew1 + (size_t)e * GIN * HIDN;
    short8 o;
#pragma unroll
    for (int j = 0; j < 8; j++) o[j] = (short)f2bf(W[(size_t)(k0 + j) * HIDN + n]);
    *(short8*)(EWF + ((((size_t)e * NKS + ks) * 32 + nt) * 64 + l) * 8) = o;
    return;
  }
  t -= 327680;
  if (t < Bn + 1) y[t] = 0.f;
  else if (t < Bn + 1 + KE) cnt[t - (Bn + 1)] = 0;
}

// ---------------- gate: split-bf16 MFMA, deep pipeline, no K-loop barriers --
// grid (256 rowgroups, 8 col-blocks of 64); wave owns one 16-col tile.
__global__ __launch_bounds__(256) void gate_kernel(
    const unsigned short* __restrict__ SH, const unsigned short* __restrict__ SL,
    const unsigned short* __restrict__ GWF, const float* __restrict__ gb1,
    const float* __restrict__ gw2, float* __restrict__ glp) {
  __shared__ __align__(16) unsigned short bsh[4][NKS][2][512];  // 80 KB
  const int tid = threadIdx.x, lane = tid & 63, wv = tid >> 6;
  const int row0 = blockIdx.x * 16, nb = blockIdx.y;
  const int nt = nb * 4 + wv;
  const int ko = (lane >> 4) * 8;
  const size_t rr = (size_t)(row0 + (lane & 15)) * GIN;

  // --- A: issue all 20 gathers to registers ---
  short8 ah[NKS], al[NKS];
#pragma unroll
  for (int ks = 0; ks < NKS; ks++) ah[ks] = *(const short8*)(SH + rr + ks * 32 + ko);
#pragma unroll
  for (int ks = 0; ks < NKS; ks++) al[ks] = *(const short8*)(SL + rr + ks * 32 + ko);
  __builtin_amdgcn_sched_barrier(0);
  // --- B: issue all 20 global_load_lds in ks order ---
#pragma unroll
  for (int ks = 0; ks < NKS; ks++) {
    gload_lds16(GWF + ((size_t)(ks * 32 + nt)) * 512 + lane * 8,
                &bsh[wv][ks][0][0]);
    gload_lds16(GWF + ((size_t)((NKS + ks) * 32 + nt)) * 512 + lane * 8,
                &bsh[wv][ks][1][0]);
  }
  __builtin_amdgcn_sched_barrier(0);

  f32x4 acc = {};
#pragma unroll
  for (int ks = 0; ks < NKS; ks++) {
    vwait(18 - 2 * ks);
    short8 bh = *(const short8*)&bsh[wv][ks][0][lane * 8];
    short8 bl = *(const short8*)&bsh[wv][ks][1][lane * 8];
    acc = __builtin_amdgcn_mfma_f32_16x16x32_bf16(ah[ks], bh, acc, 0, 0, 0);
    acc = __builtin_amdgcn_mfma_f32_16x16x32_bf16(al[ks], bh, acc, 0, 0, 0);
    acc = __builtin_amdgcn_mfma_f32_16x16x32_bf16(ah[ks], bl, acc, 0, 0, 0);
  }
  __syncthreads();  // all waves done with bsh; reuse for hs/g2s

  float (*hs)[68] = (float(*)[68])&bsh[0][0][0][0];          // 16x68 fp32
  float (*g2s)[16] = (float(*)[16])((char*)hs + 16 * 68 * 4); // 64x16 fp32
  {
    const float4* src = (const float4*)(gw2 + (size_t)nb * 64 * KE);
    if (tid < 256) ((float4*)g2s)[tid] = src[tid];
  }
  {
    int cl = wv * 16 + (lane & 15);
    float b = gb1[nb * 64 + cl];
#pragma unroll
    for (int j = 0; j < 4; j++)
      hs[(lane >> 4) * 4 + j][cl] = fmaxf(acc[j] + b, 0.f);
  }
  __syncthreads();
  {
    int row = tid >> 4, q = tid & 15;
    float s = 0.f;
#pragma unroll 8
    for (int c = 0; c < 64; c++) s = fmaf(hs[row][c], g2s[c][q], s);
    glp[((size_t)nb * Bn + row0 + row) * KE + q] = s;
  }
}

// ---------------- gate2: sum 8 partials, softmax, top-2, bucket -------------
__global__ __launch_bounds__(256) void gate2_kernel(
    const float* __restrict__ glp, const float* __restrict__ gb2,
    int* __restrict__ cnt, int* __restrict__ list, float* __restrict__ wlist) {
  __shared__ int lcnt[KE];
  __shared__ int gbase[KE];
  const int tid = threadIdx.x;
  const int row = blockIdx.x * 256 + tid;
  if (tid < KE) lcnt[tid] = 0;
  __syncthreads();
  float lg[KE];
  {
    const float4* c = (const float4*)gb2;
#pragma unroll
    for (int u = 0; u < 4; u++) {
      float4 s = c[u];
      lg[u * 4 + 0] = s.x; lg[u * 4 + 1] = s.y;
      lg[u * 4 + 2] = s.z; lg[u * 4 + 3] = s.w;
    }
#pragma unroll
    for (int sl = 0; sl < 8; sl++) {
      const float4* a = (const float4*)(glp + ((size_t)sl * Bn + row) * KE);
#pragma unroll
      for (int u = 0; u < 4; u++) {
        float4 v = a[u];
        lg[u * 4 + 0] += v.x; lg[u * 4 + 1] += v.y;
        lg[u * 4 + 2] += v.z; lg[u * 4 + 3] += v.w;
      }
    }
  }
  float m = lg[0];
#pragma unroll
  for (int q = 1; q < KE; q++) m = fmaxf(m, lg[q]);
  float e[KE];
#pragma unroll
  for (int q = 0; q < KE; q++) e[q] = expf(lg[q] - m);
  int i1 = 0; float v1 = e[0];
#pragma unroll
  for (int q = 1; q < KE; q++) if (e[q] > v1) { v1 = e[q]; i1 = q; }
  int i2 = (i1 == 0) ? 1 : 0; float v2 = e[i2];
#pragma unroll
  for (int q = 0; q < KE; q++)
    if (q != i1 && e[q] > v2) { v2 = e[q]; i2 = q; }
  int o1 = atomicAdd(&lcnt[i1], 1);
  int o2 = atomicAdd(&lcnt[i2], 1);
  __syncthreads();
  if (tid < KE) gbase[tid] = atomicAdd(&cnt[tid], lcnt[tid]);
  __syncthreads();
  float den = v1 + v2;
  int s1 = gbase[i1] + o1;
  list[i1 * Bn + s1] = row; wlist[i1 * Bn + s1] = v1 / den;
  int s2 = gbase[i2] + o2;
  list[i2 * Bn + s2] = row; wlist[i2 * Bn + s2] = v2 / den;
}

// ---------------- experts: deep pipeline, no K-loop barriers ----------------
// grid (272 chunks of 32 rows, 8 col-blocks of 64); wave owns one 16-col tile.
__global__ __launch_bounds__(256) void expert_kernel(
    const unsigned short* __restrict__ XE, const unsigned short* __restrict__ EWF,
    const float* __restrict__ eb1, const float* __restrict__ ew2,
    const float* __restrict__ eb2, const int* __restrict__ cnt,
    const int* __restrict__ list, const float* __restrict__ wlist,
    float* __restrict__ y) {
  __shared__ __align__(16) unsigned short besh[4][NKS][512];  // 40 KB
  __shared__ int rid[32];
  __shared__ float rw[32];
  const int tid = threadIdx.x, lane = tid & 63, wv = tid >> 6;
  const int item = blockIdx.x, ch = blockIdx.y;
  int k = -1, base = 0, pref = 0;
#pragma unroll
  for (int q = 0; q < KE; q++) {
    int nc = (cnt[q] + 31) >> 5;
    if (item >= pref && item < pref + nc) { k = q; base = (item - pref) * 32; }
    pref += nc;
  }
  if (k < 0) return;
  const int n = cnt[k];
  if (tid < 32) {
    int p = base + tid;
    rid[tid] = (p < n) ? list[k * Bn + p] : 0;
    rw[tid] = (p < n) ? wlist[k * Bn + p] : 0.f;
  }
  __syncthreads();
  const int nt = ch * 4 + wv;
  const int ko = (lane >> 4) * 8;
  const size_t r0 = (size_t)rid[lane & 15] * GIN;
  const size_t r1 = (size_t)rid[16 + (lane & 15)] * GIN;

  // --- A: issue all 20 gathers to registers ---
  short8 a0[NKS], a1[NKS];
#pragma unroll
  for (int ks = 0; ks < NKS; ks++) a0[ks] = *(const short8*)(XE + r0 + ks * 32 + ko);
#pragma unroll
  for (int ks = 0; ks < NKS; ks++) a1[ks] = *(const short8*)(XE + r1 + ks * 32 + ko);
  __builtin_amdgcn_sched_barrier(0);
  // --- B: issue all 10 global_load_lds in ks order ---
  const unsigned short* Wk = EWF + ((size_t)k * NKS * 32 + nt) * 512 + lane * 8;
#pragma unroll
  for (int ks = 0; ks < NKS; ks++)
    gload_lds16(Wk + (size_t)ks * 32 * 512, &besh[wv][ks][0]);
  __builtin_amdgcn_sched_barrier(0);

  f32x4 acc0 = {}, acc1 = {};
#pragma unroll
  for (int ks = 0; ks < NKS; ks++) {
    vwait(9 - ks);
    short8 b = *(const short8*)&besh[wv][ks][lane * 8];
    acc0 = __builtin_amdgcn_mfma_f32_16x16x32_bf16(a0[ks], b, acc0, 0, 0, 0);
    acc1 = __builtin_amdgcn_mfma_f32_16x16x32_bf16(a1[ks], b, acc1, 0, 0, 0);
  }

  // epilogue: bias + relu + dot w2 + reduce over 16 col-lanes + gated atomic
  const int colg = ch * 64 + wv * 16 + (lane & 15);
  const float b1v = eb1[(size_t)k * HIDN + colg];
  const float w2 = ew2[(size_t)k * HIDN + colg];
  float part[2][4];
#pragma unroll
  for (int j = 0; j < 4; j++) {
    part[0][j] = fmaxf(acc0[j] + b1v, 0.f) * w2;
    part[1][j] = fmaxf(acc1[j] + b1v, 0.f) * w2;
  }
#pragma unroll
  for (int off = 8; off >= 1; off >>= 1)
#pragma unroll
    for (int mt = 0; mt < 2; mt++)
#pragma unroll
      for (int j = 0; j < 4; j++)
        part[mt][j] += __shfl_xor(part[mt][j], off);
  if ((lane & 15) == 0) {
    float e2 = (ch == 0) ? eb2[k] : 0.f;
#pragma unroll
    for (int mt = 0; mt < 2; mt++)
#pragma unroll
      for (int j = 0; j < 4; j++) {
        int rl = mt * 16 + (lane >> 4) * 4 + j;
        atomicAdd(&y[rid[rl]], rw[rl] * (part[mt][j] + e2));
      }
  }
}

// ---------------- loss ------------------------------------------------------
__global__ __launch_bounds__(256) void loss_kernel(const int* __restrict__ cnt,
                                                   const float* __restrict__ wlist,
                                                   float* __restrict__ out) {
  __shared__ float simp[KE][KE];
  __shared__ float fimp[KE];
  const int tid = threadIdx.x;
  const int k = tid >> 4, g = tid & 15;
  const int n = cnt[k];
  float s = 0.f;
  for (int j = g; j < n; j += 16) s += wlist[k * Bn + j];
  simp[k][g] = s;
  __syncthreads();
  if (tid < KE) {
    float t = 0.f;
    for (int q = 0; q < KE; q++) t += simp[tid][q];
    fimp[tid] = t;
  }
  __syncthreads();
  if (tid == 0) {
    double mi = 0.0, ml = 0.0;
    for (int q = 0; q < KE; q++) { mi += fimp[q]; ml += (double)cnt[q]; }
    mi /= KE; ml /= KE;
    double vi = 0.0, vl = 0.0;
    for (int q = 0; q < KE; q++) {
      double di = fimp[q] - mi; vi += di * di;
      double dl = (double)cnt[q] - ml; vl += dl * dl;
    }
    vi /= KE; vl /= KE;
    out[Bn] = (float)(vi / (mi * mi + 1e-10) + vl / (ml * ml + 1e-10));
  }
}

extern "C" void kernel_launch(void* const* d_in, const int* in_sizes, int n_in,
                              void* d_out, int out_size, void* d_ws, size_t ws_size,
                              hipStream_t stream) {
  const int* x      = (const int*)d_in[0];
  const int* sql    = (const int*)d_in[1];
  const float* semb = (const float*)d_in[2];
  const float* demb = (const float*)d_in[3];
  const float* gw1  = (const float*)d_in[4];
  const float* gb1  = (const float*)d_in[5];
  const float* gw2  = (const float*)d_in[6];
  const float* gb2  = (const float*)d_in[7];
  const float* ew1  = (const float*)d_in[8];
  const float* eb1  = (const float*)d_in[9];
  const float* ew2  = (const float*)d_in[10];
  const float* eb2  = (const float*)d_in[11];
  float* y = (float*)d_out;

  char* ws = (char*)d_ws;
  int* cnt            = (int*)(ws);                        // 64 B
  int* list           = (int*)(ws + 4096);                 // 256 KB
  float* wlist        = (float*)(ws + 266240);             // 256 KB
  float* glp          = (float*)(ws + 528384);             // 2 MB (8 slices)
  unsigned short* XE  = (unsigned short*)(ws + 2625536);   // 2.62 MB
  unsigned short* SH  = (unsigned short*)(ws + 5246976);   // 2.62 MB
  unsigned short* SL  = (unsigned short*)(ws + 7868416);   // 2.62 MB
  unsigned short* GWF = (unsigned short*)(ws + 10489856);  // 655 KB
  unsigned short* EWF = (unsigned short*)(ws + 11145216);  // 5.24 MB -> 15.6 MB

  prep_kernel<<<2097, 256, 0, stream>>>(x, sql, demb, semb, gw1, ew1,
                                        XE, SH, SL, GWF, EWF, y, cnt);
  gate_kernel<<<dim3(Bn / 16, 8), 256, 0, stream>>>(SH, SL, GWF, gb1, gw2, glp);
  gate2_kernel<<<Bn / 256, 256, 0, stream>>>(glp, gb2, cnt, list, wlist);
  expert_kernel<<<dim3(272, 8), 256, 0, stream>>>(XE, EWF, eb1, ew2, eb2,
                                                  cnt, list, wlist, y);
  loss_kernel<<<1, 256, 0, stream>>>(cnt, wlist, y);
}

// Round 7
// 100.125 us; speedup vs baseline: 2.1009x; 2.1009x over previous
//
#include <hip/hip_runtime.h>

#define Bn 4096
#define NF 20
#define NEMB 16
#define HIDN 512
#define KE 16
#define GIN 320
#define NKS 10   // K-steps of 32

typedef __attribute__((ext_vector_type(8))) short short8;
typedef __attribute__((ext_vector_type(4))) float f32x4;

__device__ __forceinline__ unsigned short f2bf(float f) {
  unsigned int u = __builtin_bit_cast(unsigned int, f);
  u += 0x7fff + ((u >> 16) & 1);
  return (unsigned short)(u >> 16);
}
__device__ __forceinline__ float bf2f(unsigned short h) {
  unsigned int u = ((unsigned int)h) << 16;
  return __builtin_bit_cast(float, u);
}

__device__ __forceinline__ void gload_lds16(const unsigned short* g, void* l) {
  __builtin_amdgcn_global_load_lds(
      (const __attribute__((address_space(1))) unsigned int*)g,
      (__attribute__((address_space(3))) unsigned int*)l, 16, 0, 0);
}

// counted vmcnt wait + scheduling fence (rule #18)
__device__ __forceinline__ void vwait(int n) {
  switch (n) {
#define C(N) case N: asm volatile("s_waitcnt vmcnt(" #N ")" ::: "memory"); break;
    C(0) C(1) C(2) C(3) C(4) C(5) C(6) C(7) C(8) C(9)
    C(10) C(11) C(12) C(13) C(14) C(15) C(16) C(17) C(18)
#undef C
    default: asm volatile("s_waitcnt vmcnt(0)" ::: "memory"); break;
  }
  __builtin_amdgcn_sched_barrier(0);
}

// ---------------- prep: gathers, bf16 conversion, fragment-ordered weights --
__global__ __launch_bounds__(256) void prep_kernel(
    const int* __restrict__ x, const int* __restrict__ sql,
    const float* __restrict__ demb, const float* __restrict__ semb,
    const float* __restrict__ gw1, const float* __restrict__ ew1,
    unsigned short* __restrict__ XE, unsigned short* __restrict__ SH,
    unsigned short* __restrict__ SL, unsigned short* __restrict__ GWF,
    unsigned short* __restrict__ EWF, float* __restrict__ y,
    int* __restrict__ cnt) {
  long long t = (long long)blockIdx.x * 256 + threadIdx.x;
  if (t < 81920) {
    int row = (int)(t / NF), f = (int)(t % NF);
    int idx = x[row * NF + f];
    const float* s = demb + (size_t)idx * NEMB;
    short8 o0, o1;
#pragma unroll
    for (int i = 0; i < 8; i++) {
      o0[i] = (short)f2bf(s[i]);
      o1[i] = (short)f2bf(s[8 + i]);
    }
    size_t o = (size_t)row * GIN + f * NEMB;
    *(short8*)(XE + o) = o0;
    *(short8*)(XE + o + 8) = o1;
    return;
  }
  t -= 81920;
  if (t < 81920) {
    int row = (int)(t / NF), f = (int)(t % NF);
    int idx = sql[row * NF + f];
    const float* s = semb + (size_t)idx * NEMB;
    short8 h0, h1, l0, l1;
#pragma unroll
    for (int i = 0; i < 8; i++) {
      float v = s[i];
      unsigned short hb = f2bf(v);
      h0[i] = (short)hb; l0[i] = (short)f2bf(v - bf2f(hb));
      v = s[8 + i];
      hb = f2bf(v);
      h1[i] = (short)hb; l1[i] = (short)f2bf(v - bf2f(hb));
    }
    size_t o = (size_t)row * GIN + f * NEMB;
    *(short8*)(SH + o) = h0; *(short8*)(SH + o + 8) = h1;
    *(short8*)(SL + o) = l0; *(short8*)(SL + o + 8) = l1;
    return;
  }
  t -= 81920;
  if (t < 40960) {
    int s = (int)(t / 20480), r = (int)(t % 20480);
    int ks = r / 2048, r2 = r % 2048, nt = r2 / 64, l = r2 % 64;
    int k0 = ks * 32 + (l >> 4) * 8, n = nt * 16 + (l & 15);
    short8 o;
#pragma unroll
    for (int j = 0; j < 8; j++) {
      float w = gw1[(size_t)(k0 + j) * HIDN + n];
      unsigned short hb = f2bf(w);
      o[j] = (s == 0) ? (short)hb : (short)f2bf(w - bf2f(hb));
    }
    *(short8*)(GWF + ((((size_t)s * NKS + ks) * 32 + nt) * 64 + l) * 8) = o;
    return;
  }
  t -= 40960;
  if (t < 327680) {
    int e = (int)(t / 20480), r = (int)(t % 20480);
    int ks = r / 2048, r2 = r % 2048, nt = r2 / 64, l = r2 % 64;
    int k0 = ks * 32 + (l >> 4) * 8, n = nt * 16 + (l & 15);
    const float* W = ew1 + (size_t)e * GIN * HIDN;
    short8 o;
#pragma unroll
    for (int j = 0; j < 8; j++) o[j] = (short)f2bf(W[(size_t)(k0 + j) * HIDN + n]);
    *(short8*)(EWF + ((((size_t)e * NKS + ks) * 32 + nt) * 64 + l) * 8) = o;
    return;
  }
  t -= 327680;
  if (t < Bn + 1) y[t] = 0.f;
  else if (t < Bn + 1 + KE) cnt[t - (Bn + 1)] = 0;
}

// ---------------- gate: split-bf16 MFMA, 6-deep LDS ring, no K-loop barriers
// grid (256 rowgroups, 8 col-blocks of 64); wave owns one 16-col tile.
// A: 20 frags in regs (80 VGPR) -> launch_bounds cap must allow ~120.
__global__ __launch_bounds__(256, 3) void gate_kernel(
    const unsigned short* __restrict__ SH, const unsigned short* __restrict__ SL,
    const unsigned short* __restrict__ GWF, const float* __restrict__ gb1,
    const float* __restrict__ gw2, float* __restrict__ glp) {
  __shared__ __align__(16) unsigned short bsh[4][6][2][512];  // 48 KB ring
  const int tid = threadIdx.x, lane = tid & 63, wv = tid >> 6;
  const int row0 = blockIdx.x * 16, nb = blockIdx.y;
  const int ntg = nb * 4 + wv;
  const int ko = (lane >> 4) * 8;
  const size_t rr = (size_t)(row0 + (lane & 15)) * GIN;

  // A: issue all 20 gathers to registers (first in issue order)
  short8 ah[NKS], al[NKS];
#pragma unroll
  for (int ks = 0; ks < NKS; ks++) ah[ks] = *(const short8*)(SH + rr + ks * 32 + ko);
#pragma unroll
  for (int ks = 0; ks < NKS; ks++) al[ks] = *(const short8*)(SL + rr + ks * 32 + ko);
  __builtin_amdgcn_sched_barrier(0);
  // B: prologue pairs 0..5 into ring slots 0..5
#pragma unroll
  for (int p = 0; p < 6; p++) {
    gload_lds16(GWF + ((size_t)(p * 32 + ntg)) * 512 + lane * 8, &bsh[wv][p][0][0]);
    gload_lds16(GWF + ((size_t)((NKS + p) * 32 + ntg)) * 512 + lane * 8,
                &bsh[wv][p][1][0]);
  }
  __builtin_amdgcn_sched_barrier(0);

  f32x4 acc = {};
#pragma unroll
  for (int ks = 0; ks < NKS; ks++) {
    int w = 2 * (NKS - 1 - ks); if (w > 10) w = 10;
    vwait(w);                              // pair ks retired
    short8 bh = *(const short8*)&bsh[wv][ks % 6][0][lane * 8];
    short8 bl = *(const short8*)&bsh[wv][ks % 6][1][lane * 8];
    acc = __builtin_amdgcn_mfma_f32_16x16x32_bf16(ah[ks], bh, acc, 0, 0, 0);
    acc = __builtin_amdgcn_mfma_f32_16x16x32_bf16(al[ks], bh, acc, 0, 0, 0);
    acc = __builtin_amdgcn_mfma_f32_16x16x32_bf16(ah[ks], bl, acc, 0, 0, 0);
    __builtin_amdgcn_sched_barrier(0);     // keep re-issue below the reads
    if (ks + 6 < NKS) {
      const int p = ks + 6, s = ks % 6;    // compile-time under full unroll
      gload_lds16(GWF + ((size_t)(p * 32 + ntg)) * 512 + lane * 8, &bsh[wv][s][0][0]);
      gload_lds16(GWF + ((size_t)((NKS + p) * 32 + ntg)) * 512 + lane * 8,
                  &bsh[wv][s][1][0]);
    }
  }
  __syncthreads();  // all waves done with bsh; reuse for hs/g2s

  float (*hs)[68] = (float(*)[68])&bsh[0][0][0][0];            // 16x68 fp32
  float (*g2s)[16] = (float(*)[16])((char*)&bsh[0][0][0][0] + 16 * 68 * 4);
  {
    const float4* src = (const float4*)(gw2 + (size_t)nb * 64 * KE);
    ((float4*)g2s)[tid] = src[tid];        // 64x16 floats = 256 float4
  }
  {
    int cl = wv * 16 + (lane & 15);
    float b = gb1[nb * 64 + cl];
#pragma unroll
    for (int j = 0; j < 4; j++)
      hs[(lane >> 4) * 4 + j][cl] = fmaxf(acc[j] + b, 0.f);
  }
  __syncthreads();
  {
    int row = tid >> 4, q = tid & 15;
    float s = 0.f;
#pragma unroll 8
    for (int c = 0; c < 64; c++) s = fmaf(hs[row][c], g2s[c][q], s);
    glp[((size_t)nb * Bn + row0 + row) * KE + q] = s;
  }
}

// ---------------- gate2: sum 8 partials, softmax, top-2, bucket -------------
__global__ __launch_bounds__(256) void gate2_kernel(
    const float* __restrict__ glp, const float* __restrict__ gb2,
    int* __restrict__ cnt, int* __restrict__ list, float* __restrict__ wlist) {
  __shared__ int lcnt[KE];
  __shared__ int gbase[KE];
  const int tid = threadIdx.x;
  const int row = blockIdx.x * 256 + tid;
  if (tid < KE) lcnt[tid] = 0;
  __syncthreads();
  float lg[KE];
  {
    const float4* c = (const float4*)gb2;
#pragma unroll
    for (int u = 0; u < 4; u++) {
      float4 s = c[u];
      lg[u * 4 + 0] = s.x; lg[u * 4 + 1] = s.y;
      lg[u * 4 + 2] = s.z; lg[u * 4 + 3] = s.w;
    }
#pragma unroll
    for (int sl = 0; sl < 8; sl++) {
      const float4* a = (const float4*)(glp + ((size_t)sl * Bn + row) * KE);
#pragma unroll
      for (int u = 0; u < 4; u++) {
        float4 v = a[u];
        lg[u * 4 + 0] += v.x; lg[u * 4 + 1] += v.y;
        lg[u * 4 + 2] += v.z; lg[u * 4 + 3] += v.w;
      }
    }
  }
  float m = lg[0];
#pragma unroll
  for (int q = 1; q < KE; q++) m = fmaxf(m, lg[q]);
  float e[KE];
#pragma unroll
  for (int q = 0; q < KE; q++) e[q] = expf(lg[q] - m);
  int i1 = 0; float v1 = e[0];
#pragma unroll
  for (int q = 1; q < KE; q++) if (e[q] > v1) { v1 = e[q]; i1 = q; }
  int i2 = (i1 == 0) ? 1 : 0; float v2 = e[i2];
#pragma unroll
  for (int q = 0; q < KE; q++)
    if (q != i1 && e[q] > v2) { v2 = e[q]; i2 = q; }
  int o1 = atomicAdd(&lcnt[i1], 1);
  int o2 = atomicAdd(&lcnt[i2], 1);
  __syncthreads();
  if (tid < KE) gbase[tid] = atomicAdd(&cnt[tid], lcnt[tid]);
  __syncthreads();
  float den = v1 + v2;
  int s1 = gbase[i1] + o1;
  list[i1 * Bn + s1] = row; wlist[i1 * Bn + s1] = v1 / den;
  int s2 = gbase[i2] + o2;
  list[i2 * Bn + s2] = row; wlist[i2 * Bn + s2] = v2 / den;
}

// ---------------- experts: 16-row chunks, barrier-free, counted vmcnt -------
// grid (527 chunk-slots, 8 col-blocks of 64); wave owns one 16-col tile.
// A: 10 frags = 40 VGPR. No __syncthreads anywhere.
__global__ __launch_bounds__(256, 4) void expert_kernel(
    const unsigned short* __restrict__ XE, const unsigned short* __restrict__ EWF,
    const float* __restrict__ eb1, const float* __restrict__ ew2,
    const float* __restrict__ eb2, const int* __restrict__ cnt,
    const int* __restrict__ list, const float* __restrict__ wlist,
    float* __restrict__ y) {
  __shared__ __align__(16) unsigned short bsh[4][NKS][512];  // 40 KB
  const int tid = threadIdx.x, lane = tid & 63, wv = tid >> 6;
  const int item = blockIdx.x, ch = blockIdx.y;
  int k = -1, base = 0, pref = 0;
#pragma unroll
  for (int q = 0; q < KE; q++) {
    int nc = (cnt[q] + 15) >> 4;
    if (item >= pref && item < pref + nc) { k = q; base = (item - pref) * 16; }
    pref += nc;
  }
  if (k < 0) return;
  const int n = cnt[k];
  const int ko = (lane >> 4) * 8;
  const int pl = base + (lane & 15);
  const int ridl = (pl < n) ? list[k * Bn + pl] : 0;  // clamp: no OOB gathers
  const size_t r0 = (size_t)ridl * GIN;

  // A: issue 10 gathers to registers (first in issue order)
  short8 a[NKS];
#pragma unroll
  for (int ks = 0; ks < NKS; ks++) a[ks] = *(const short8*)(XE + r0 + ks * 32 + ko);
  __builtin_amdgcn_sched_barrier(0);
  // B: issue all 10 global_load_lds in ks order (per-wave strip)
  const unsigned short* Wk =
      EWF + ((size_t)k * NKS * 32 + ch * 4 + wv) * 512 + lane * 8;
#pragma unroll
  for (int ks = 0; ks < NKS; ks++)
    gload_lds16(Wk + (size_t)ks * 32 * 512, &bsh[wv][ks][0]);
  __builtin_amdgcn_sched_barrier(0);

  f32x4 acc = {};
#pragma unroll
  for (int ks = 0; ks < NKS; ks++) {
    vwait(NKS - 1 - ks);
    short8 b = *(const short8*)&bsh[wv][ks][lane * 8];
    acc = __builtin_amdgcn_mfma_f32_16x16x32_bf16(a[ks], b, acc, 0, 0, 0);
  }

  // epilogue: bias + relu + dot w2 + reduce over 16 col-lanes + gated atomic
  const int colg = ch * 64 + wv * 16 + (lane & 15);
  const float b1v = eb1[(size_t)k * HIDN + colg];
  const float w2 = ew2[(size_t)k * HIDN + colg];
  float part[4];
#pragma unroll
  for (int j = 0; j < 4; j++) part[j] = fmaxf(acc[j] + b1v, 0.f) * w2;
#pragma unroll
  for (int off = 8; off >= 1; off >>= 1)
#pragma unroll
    for (int j = 0; j < 4; j++) part[j] += __shfl_xor(part[j], off);
  if ((lane & 15) == 0) {
    float e2 = (ch == 0) ? eb2[k] : 0.f;
#pragma unroll
    for (int j = 0; j < 4; j++) {
      int r = (lane >> 4) * 4 + j;
      int pp = base + r;
      if (pp < n) {
        int rd = list[k * Bn + pp];
        float rwv = wlist[k * Bn + pp];
        atomicAdd(&y[rd], rwv * (part[j] + e2));
      }
    }
  }
}

// ---------------- loss ------------------------------------------------------
__global__ __launch_bounds__(256) void loss_kernel(const int* __restrict__ cnt,
                                                   const float* __restrict__ wlist,
                                                   float* __restrict__ out) {
  __shared__ float simp[KE][KE];
  __shared__ float fimp[KE];
  const int tid = threadIdx.x;
  const int k = tid >> 4, g = tid & 15;
  const int n = cnt[k];
  float s = 0.f;
  for (int j = g; j < n; j += 16) s += wlist[k * Bn + j];
  simp[k][g] = s;
  __syncthreads();
  if (tid < KE) {
    float t = 0.f;
    for (int q = 0; q < KE; q++) t += simp[tid][q];
    fimp[tid] = t;
  }
  __syncthreads();
  if (tid == 0) {
    double mi = 0.0, ml = 0.0;
    for (int q = 0; q < KE; q++) { mi += fimp[q]; ml += (double)cnt[q]; }
    mi /= KE; ml /= KE;
    double vi = 0.0, vl = 0.0;
    for (int q = 0; q < KE; q++) {
      double di = fimp[q] - mi; vi += di * di;
      double dl = (double)cnt[q] - ml; vl += dl * dl;
    }
    vi /= KE; vl /= KE;
    out[Bn] = (float)(vi / (mi * mi + 1e-10) + vl / (ml * ml + 1e-10));
  }
}

extern "C" void kernel_launch(void* const* d_in, const int* in_sizes, int n_in,
                              void* d_out, int out_size, void* d_ws, size_t ws_size,
                              hipStream_t stream) {
  const int* x      = (const int*)d_in[0];
  const int* sql    = (const int*)d_in[1];
  const float* semb = (const float*)d_in[2];
  const float* demb = (const float*)d_in[3];
  const float* gw1  = (const float*)d_in[4];
  const float* gb1  = (const float*)d_in[5];
  const float* gw2  = (const float*)d_in[6];
  const float* gb2  = (const float*)d_in[7];
  const float* ew1  = (const float*)d_in[8];
  const float* eb1  = (const float*)d_in[9];
  const float* ew2  = (const float*)d_in[10];
  const float* eb2  = (const float*)d_in[11];
  float* y = (float*)d_out;

  char* ws = (char*)d_ws;
  int* cnt            = (int*)(ws);                        // 64 B
  int* list           = (int*)(ws + 4096);                 // 256 KB
  float* wlist        = (float*)(ws + 266240);             // 256 KB
  float* glp          = (float*)(ws + 528384);             // 2 MB (8 slices)
  unsigned short* XE  = (unsigned short*)(ws + 2625536);   // 2.62 MB
  unsigned short* SH  = (unsigned short*)(ws + 5246976);   // 2.62 MB
  unsigned short* SL  = (unsigned short*)(ws + 7868416);   // 2.62 MB
  unsigned short* GWF = (unsigned short*)(ws + 10489856);  // 655 KB
  unsigned short* EWF = (unsigned short*)(ws + 11145216);  // 5.24 MB -> 16.4 MB

  prep_kernel<<<2097, 256, 0, stream>>>(x, sql, demb, semb, gw1, ew1,
                                        XE, SH, SL, GWF, EWF, y, cnt);
  gate_kernel<<<dim3(Bn / 16, 8), 256, 0, stream>>>(SH, SL, GWF, gb1, gw2, glp);
  gate2_kernel<<<Bn / 256, 256, 0, stream>>>(glp, gb2, cnt, list, wlist);
  expert_kernel<<<dim3(527, 8), 256, 0, stream>>>(XE, EWF, eb1, ew2, eb2,
                                                  cnt, list, wlist, y);
  loss_kernel<<<1, 256, 0, stream>>>(cnt, wlist, y);
}

// Round 8
// 82.091 us; speedup vs baseline: 2.5624x; 1.2197x over previous
//
#include <hip/hip_runtime.h>

#define Bn 4096
#define NF 20
#define NEMB 16
#define HIDN 512
#define KE 16
#define GIN 320
#define NKS 10   // K-steps of 32

typedef __attribute__((ext_vector_type(8))) short short8;
typedef __attribute__((ext_vector_type(4))) float f32x4;

__device__ __forceinline__ unsigned short f2bf(float f) {
  unsigned int u = __builtin_bit_cast(unsigned int, f);
  u += 0x7fff + ((u >> 16) & 1);
  return (unsigned short)(u >> 16);
}
__device__ __forceinline__ float bf2f(unsigned short h) {
  unsigned int u = ((unsigned int)h) << 16;
  return __builtin_bit_cast(float, u);
}

__device__ __forceinline__ void gload_lds16(const unsigned short* g, void* l) {
  __builtin_amdgcn_global_load_lds(
      (const __attribute__((address_space(1))) unsigned int*)g,
      (__attribute__((address_space(3))) unsigned int*)l, 16, 0, 0);
}

// counted vmcnt wait (multiples of 5 only) + scheduling fence (rule #18)
__device__ __forceinline__ void vwaitN(int n) {
  if (n >= 15)      asm volatile("s_waitcnt vmcnt(15)" ::: "memory");
  else if (n >= 10) asm volatile("s_waitcnt vmcnt(10)" ::: "memory");
  else if (n >= 5)  asm volatile("s_waitcnt vmcnt(5)" ::: "memory");
  else              asm volatile("s_waitcnt vmcnt(0)" ::: "memory");
  __builtin_amdgcn_sched_barrier(0);
}

// ---------------- prep: gathers, bf16 conversion, fragment-ordered weights --
__global__ __launch_bounds__(256) void prep_kernel(
    const int* __restrict__ x, const int* __restrict__ sql,
    const float* __restrict__ demb, const float* __restrict__ semb,
    const float* __restrict__ gw1, const float* __restrict__ ew1,
    unsigned short* __restrict__ XE, unsigned short* __restrict__ SH,
    unsigned short* __restrict__ SL, unsigned short* __restrict__ GWF,
    unsigned short* __restrict__ EWF, float* __restrict__ y,
    int* __restrict__ cnt) {
  long long t = (long long)blockIdx.x * 256 + threadIdx.x;
  if (t < 81920) {
    int row = (int)(t / NF), f = (int)(t % NF);
    int idx = x[row * NF + f];
    const float* s = demb + (size_t)idx * NEMB;
    short8 o0, o1;
#pragma unroll
    for (int i = 0; i < 8; i++) {
      o0[i] = (short)f2bf(s[i]);
      o1[i] = (short)f2bf(s[8 + i]);
    }
    size_t o = (size_t)row * GIN + f * NEMB;
    *(short8*)(XE + o) = o0;
    *(short8*)(XE + o + 8) = o1;
    return;
  }
  t -= 81920;
  if (t < 81920) {
    int row = (int)(t / NF), f = (int)(t % NF);
    int idx = sql[row * NF + f];
    const float* s = semb + (size_t)idx * NEMB;
    short8 h0, h1, l0, l1;
#pragma unroll
    for (int i = 0; i < 8; i++) {
      float v = s[i];
      unsigned short hb = f2bf(v);
      h0[i] = (short)hb; l0[i] = (short)f2bf(v - bf2f(hb));
      v = s[8 + i];
      hb = f2bf(v);
      h1[i] = (short)hb; l1[i] = (short)f2bf(v - bf2f(hb));
    }
    size_t o = (size_t)row * GIN + f * NEMB;
    *(short8*)(SH + o) = h0; *(short8*)(SH + o + 8) = h1;
    *(short8*)(SL + o) = l0; *(short8*)(SL + o + 8) = l1;
    return;
  }
  t -= 81920;
  if (t < 40960) {
    int s = (int)(t / 20480), r = (int)(t % 20480);
    int ks = r / 2048, r2 = r % 2048, nt = r2 / 64, l = r2 % 64;
    int k0 = ks * 32 + (l >> 4) * 8, n = nt * 16 + (l & 15);
    short8 o;
#pragma unroll
    for (int j = 0; j < 8; j++) {
      float w = gw1[(size_t)(k0 + j) * HIDN + n];
      unsigned short hb = f2bf(w);
      o[j] = (s == 0) ? (short)hb : (short)f2bf(w - bf2f(hb));
    }
    *(short8*)(GWF + ((((size_t)s * NKS + ks) * 32 + nt) * 64 + l) * 8) = o;
    return;
  }
  t -= 40960;
  if (t < 327680) {
    int e = (int)(t / 20480), r = (int)(t % 20480);
    int ks = r / 2048, r2 = r % 2048, nt = r2 / 64, l = r2 % 64;
    int k0 = ks * 32 + (l >> 4) * 8, n = nt * 16 + (l & 15);
    const float* W = ew1 + (size_t)e * GIN * HIDN;
    short8 o;
#pragma unroll
    for (int j = 0; j < 8; j++) o[j] = (short)f2bf(W[(size_t)(k0 + j) * HIDN + n]);
    *(short8*)(EWF + ((((size_t)e * NKS + ks) * 32 + nt) * 64 + l) * 8) = o;
    return;
  }
  t -= 327680;
  if (t < Bn + 1) y[t] = 0.f;
  else if (t < Bn + 1 + KE) cnt[t - (Bn + 1)] = 0;
}

// ---------------- gate: split-bf16 MFMA panel pipeline ----------------------
// grid (32 rowbands of 128, 8 colblocks of 64). 8 panels of 16 rows.
// Ring-5 LDS staging (5 gloads/wave/panel), counted vmcnt, raw s_barrier.
__global__ __launch_bounds__(256) void gate_kernel(
    const unsigned short* __restrict__ SH, const unsigned short* __restrict__ SL,
    const unsigned short* __restrict__ GWF, const float* __restrict__ gb1,
    const float* __restrict__ gw2, float* __restrict__ glp) {
  __shared__ __align__(16) unsigned short ring[5][10240];  // 100 KB
  __shared__ float hs[128][68];                            // 34.8 KB
  __shared__ __align__(16) float g2s[64][16];              // 4 KB
  const int tid = threadIdx.x, lane = tid & 63, wv = tid >> 6;
  const int band = blockIdx.x * 128, cb = blockIdx.y;
  const int ntg = cb * 4 + wv;

  // gw2 slice -> LDS (1 float4/thread)
  ((float4*)g2s)[tid] = ((const float4*)(gw2 + (size_t)cb * 64 * KE))[tid];

  // B fragments in registers (hi + lo), loaded once
  short8 bh[NKS], bl[NKS];
#pragma unroll
  for (int ks = 0; ks < NKS; ks++) {
    bh[ks] = *(const short8*)(GWF + ((size_t)(ks * 32 + ntg)) * 512 + lane * 8);
    bl[ks] = *(const short8*)(GWF + ((size_t)((NKS + ks) * 32 + ntg)) * 512 + lane * 8);
  }
  __builtin_amdgcn_sched_barrier(0);

#define GSTG(pi, slot)                                                          \
  {                                                                             \
    _Pragma("unroll") for (int i = 0; i < 5; i++) {                             \
      int c = wv * 5 + i;                                                       \
      int hl = c / 10, kss = c % 10;                                            \
      const unsigned short* s_ = (hl ? SL : SH) +                               \
          (size_t)(band + (pi)*16 + (lane & 15)) * GIN + kss * 32 +             \
          (lane >> 4) * 8;                                                      \
      gload_lds16(s_, &ring[slot][c * 512 + lane * 8]);                         \
    }                                                                           \
  }

  // prologue: panels 0..3 -> slots 0..3
#pragma unroll
  for (int pp = 0; pp < 4; pp++) GSTG(pp, pp)
  __builtin_amdgcn_sched_barrier(0);

  const int cl = wv * 16 + (lane & 15);
  const float b1v = gb1[cb * 64 + cl];

#pragma unroll
  for (int p = 0; p < 8; p++) {
    int rem = 7 - p;
    vwaitN(5 * (rem > 3 ? 3 : rem));   // panel p staged (own 5 chunks retired)
    __builtin_amdgcn_s_barrier();      // all waves' chunks for panel p retired
    __builtin_amdgcn_sched_barrier(0);
    if (p + 4 < 8) GSTG(p + 4, (p + 4) % 5)
    __builtin_amdgcn_sched_barrier(0);
    const unsigned short* rb = ring[p % 5];
    f32x4 acc = {};
#pragma unroll
    for (int ks = 0; ks < NKS; ks++) {
      short8 ah = *(const short8*)&rb[ks * 512 + lane * 8];
      short8 al = *(const short8*)&rb[(NKS + ks) * 512 + lane * 8];
      acc = __builtin_amdgcn_mfma_f32_16x16x32_bf16(ah, bh[ks], acc, 0, 0, 0);
      acc = __builtin_amdgcn_mfma_f32_16x16x32_bf16(al, bh[ks], acc, 0, 0, 0);
      acc = __builtin_amdgcn_mfma_f32_16x16x32_bf16(ah, bl[ks], acc, 0, 0, 0);
    }
#pragma unroll
    for (int j = 0; j < 4; j++)
      hs[p * 16 + (lane >> 4) * 4 + j][cl] = fmaxf(acc[j] + b1v, 0.f);
  }
  __syncthreads();

  // partial logits for this 64-col slice
#pragma unroll
  for (int it = 0; it < 8; it++) {
    int row = it * 16 + (tid >> 4), q = tid & 15;
    float s = 0.f;
#pragma unroll 8
    for (int c = 0; c < 64; c++) s = fmaf(hs[row][c], g2s[c][q], s);
    glp[((size_t)cb * Bn + band + row) * KE + q] = s;
  }
#undef GSTG
}

// ---------------- gate2: sum 8 partials, softmax, top-2, bucket -------------
__global__ __launch_bounds__(256) void gate2_kernel(
    const float* __restrict__ glp, const float* __restrict__ gb2,
    int* __restrict__ cnt, int* __restrict__ list, float* __restrict__ wlist) {
  __shared__ int lcnt[KE];
  __shared__ int gbase[KE];
  const int tid = threadIdx.x;
  const int row = blockIdx.x * 256 + tid;
  if (tid < KE) lcnt[tid] = 0;
  __syncthreads();
  float lg[KE];
  {
    const float4* c = (const float4*)gb2;
#pragma unroll
    for (int u = 0; u < 4; u++) {
      float4 s = c[u];
      lg[u * 4 + 0] = s.x; lg[u * 4 + 1] = s.y;
      lg[u * 4 + 2] = s.z; lg[u * 4 + 3] = s.w;
    }
#pragma unroll
    for (int sl = 0; sl < 8; sl++) {
      const float4* a = (const float4*)(glp + ((size_t)sl * Bn + row) * KE);
#pragma unroll
      for (int u = 0; u < 4; u++) {
        float4 v = a[u];
        lg[u * 4 + 0] += v.x; lg[u * 4 + 1] += v.y;
        lg[u * 4 + 2] += v.z; lg[u * 4 + 3] += v.w;
      }
    }
  }
  float m = lg[0];
#pragma unroll
  for (int q = 1; q < KE; q++) m = fmaxf(m, lg[q]);
  float e[KE];
#pragma unroll
  for (int q = 0; q < KE; q++) e[q] = expf(lg[q] - m);
  int i1 = 0; float v1 = e[0];
#pragma unroll
  for (int q = 1; q < KE; q++) if (e[q] > v1) { v1 = e[q]; i1 = q; }
  int i2 = (i1 == 0) ? 1 : 0; float v2 = e[i2];
#pragma unroll
  for (int q = 0; q < KE; q++)
    if (q != i1 && e[q] > v2) { v2 = e[q]; i2 = q; }
  int o1 = atomicAdd(&lcnt[i1], 1);
  int o2 = atomicAdd(&lcnt[i2], 1);
  __syncthreads();
  if (tid < KE) gbase[tid] = atomicAdd(&cnt[tid], lcnt[tid]);
  __syncthreads();
  float den = v1 + v2;
  int s1 = gbase[i1] + o1;
  list[i1 * Bn + s1] = row; wlist[i1 * Bn + s1] = v1 / den;
  int s2 = gbase[i2] + o2;
  list[i2 * Bn + s2] = row; wlist[i2 * Bn + s2] = v2 / den;
}

// ---------------- pack (+loss): per-expert fragment-packed A ----------------
// grid (65, 16): jb<64 pack 64 rows of expert k; jb==64,k==0 computes loss.
__global__ __launch_bounds__(256) void packloss_kernel(
    const unsigned short* __restrict__ XE, const int* __restrict__ cnt,
    const int* __restrict__ list, const float* __restrict__ wlist,
    unsigned short* __restrict__ XEP, float* __restrict__ out) {
  __shared__ float simp[KE][KE];
  __shared__ float fimp[KE];
  const int tid = threadIdx.x;
  const int jb = blockIdx.x, k = blockIdx.y;
  if (jb == 64) {
    if (k != 0) return;
    const int kk = tid >> 4, g = tid & 15;
    const int n = cnt[kk];
    float s = 0.f;
    for (int j = g; j < n; j += 16) s += wlist[kk * Bn + j];
    simp[kk][g] = s;
    __syncthreads();
    if (tid < KE) {
      float t = 0.f;
      for (int q = 0; q < KE; q++) t += simp[tid][q];
      fimp[tid] = t;
    }
    __syncthreads();
    if (tid == 0) {
      double mi = 0.0, ml = 0.0;
      for (int q = 0; q < KE; q++) { mi += fimp[q]; ml += (double)cnt[q]; }
      mi /= KE; ml /= KE;
      double vi = 0.0, vl = 0.0;
      for (int q = 0; q < KE; q++) {
        double di = fimp[q] - mi; vi += di * di;
        double dl = (double)cnt[q] - ml; vl += dl * dl;
      }
      vi /= KE; vl /= KE;
      out[Bn] = (float)(vi / (mi * mi + 1e-10) + vl / (ml * ml + 1e-10));
    }
    return;
  }
  const int n = cnt[k];
  if (jb * 64 >= n) return;
  unsigned short* reg = XEP + (size_t)k * 1310720;
#pragma unroll
  for (int it = 0; it < 10; it++) {
    int tt = it * 256 + tid;
    int i = jb * 64 + tt / 40, c = tt % 40;
    if (i < n) {
      int ks = c >> 2, ko = c & 3;
      int rid = list[k * Bn + i];
      short8 v = *(const short8*)(XE + (size_t)rid * GIN + ks * 32 + ko * 8);
      int panel = i >> 5, r5 = i & 31, mt = r5 >> 4, lr = r5 & 15;
      *(short8*)(reg + (size_t)panel * 10240 + ks * 1024 + mt * 512 +
                 ko * 128 + lr * 8) = v;
    }
  }
}

// ---------------- experts: panel pipeline over packed A ---------------------
// grid (4 colblocks of 128, 16 experts, 4 row-quarters). Panels of 32 rows.
__global__ __launch_bounds__(256) void expert_kernel(
    const unsigned short* __restrict__ XEP, const unsigned short* __restrict__ EWF,
    const float* __restrict__ eb1, const float* __restrict__ ew2,
    const float* __restrict__ eb2, const int* __restrict__ cnt,
    const int* __restrict__ list, const float* __restrict__ wlist,
    float* __restrict__ y) {
  __shared__ __align__(16) unsigned short ring[5][10240];  // 100 KB
  __shared__ float pb[32][4][32];                          // 16 KB partials
  const int tid = threadIdx.x, lane = tid & 63, wv = tid >> 6;
  const int cb = blockIdx.x, k = blockIdx.y, qz = blockIdx.z;
  const int n = cnt[k];
  const int np = (n + 31) >> 5;
  const int npb = (np > qz) ? ((np - qz + 3) >> 2) : 0;
  if (npb == 0) return;
  const unsigned short* XEPk = XEP + (size_t)k * 1310720;
  const int kBn = k * Bn;

  // per-wave constants + B fragments (all VMEM before prologue stages)
  float b1v[2], w2v[2];
#pragma unroll
  for (int nt = 0; nt < 2; nt++) {
    int colg = cb * 128 + (wv * 2 + nt) * 16 + (lane & 15);
    b1v[nt] = eb1[(size_t)k * HIDN + colg];
    w2v[nt] = ew2[(size_t)k * HIDN + colg];
  }
  short8 bb[2][NKS];
#pragma unroll
  for (int nt = 0; nt < 2; nt++)
#pragma unroll
    for (int ks = 0; ks < NKS; ks++)
      bb[nt][ks] = *(const short8*)(
          EWF + ((size_t)((k * NKS + ks) * 32 + cb * 8 + wv * 2 + nt)) * 512 +
          lane * 8);
  __builtin_amdgcn_sched_barrier(0);

#define ESTG(pi, slot)                                                          \
  {                                                                             \
    _Pragma("unroll") for (int i = 0; i < 5; i++) {                             \
      int c = wv * 5 + i;                                                       \
      gload_lds16(XEPk + (size_t)(pi)*10240 + c * 512 + lane * 8,               \
                  &ring[slot][c * 512 + lane * 8]);                             \
    }                                                                           \
  }

  // prologue: panels 0..3 (global panel qz+4*pp) -> slots 0..3
#pragma unroll
  for (int pp = 0; pp < 4; pp++)
    if (pp < npb) ESTG(qz + 4 * pp, pp)
  __builtin_amdgcn_sched_barrier(0);

  for (int p = 0; p < npb; p++) {
    int rem = npb - 1 - p;
    vwaitN(5 * (rem > 3 ? 3 : rem));
    __builtin_amdgcn_s_barrier();
    __builtin_amdgcn_sched_barrier(0);
    if (p + 4 < npb) ESTG(qz + 4 * (p + 4), (p + 4) % 5)
    __builtin_amdgcn_sched_barrier(0);
    const unsigned short* rb = ring[p % 5];
    f32x4 acc[2][2] = {};
#pragma unroll
    for (int ks = 0; ks < NKS; ks++) {
      short8 a0 = *(const short8*)&rb[ks * 1024 + lane * 8];
      short8 a1 = *(const short8*)&rb[ks * 1024 + 512 + lane * 8];
      acc[0][0] = __builtin_amdgcn_mfma_f32_16x16x32_bf16(a0, bb[0][ks], acc[0][0], 0, 0, 0);
      acc[0][1] = __builtin_amdgcn_mfma_f32_16x16x32_bf16(a0, bb[1][ks], acc[0][1], 0, 0, 0);
      acc[1][0] = __builtin_amdgcn_mfma_f32_16x16x32_bf16(a1, bb[0][ks], acc[1][0], 0, 0, 0);
      acc[1][1] = __builtin_amdgcn_mfma_f32_16x16x32_bf16(a1, bb[1][ks], acc[1][1], 0, 0, 0);
    }
    // per-panel: relu + w2 dot + 16-lane reduce -> LDS partials (no VMEM!)
    float part[2][4];
#pragma unroll
    for (int mt = 0; mt < 2; mt++)
#pragma unroll
      for (int j = 0; j < 4; j++)
        part[mt][j] = fmaxf(acc[mt][0][j] + b1v[0], 0.f) * w2v[0] +
                      fmaxf(acc[mt][1][j] + b1v[1], 0.f) * w2v[1];
#pragma unroll
    for (int off = 8; off >= 1; off >>= 1)
#pragma unroll
      for (int mt = 0; mt < 2; mt++)
#pragma unroll
        for (int j = 0; j < 4; j++)
          part[mt][j] += __shfl_xor(part[mt][j], off);
    if ((lane & 15) == 0) {
#pragma unroll
      for (int mt = 0; mt < 2; mt++)
#pragma unroll
        for (int j = 0; j < 4; j++)
          pb[p][wv][mt * 16 + (lane >> 4) * 4 + j] = part[mt][j];
    }
  }
  __syncthreads();

  // deferred epilogue: combine 4 wave-partials, gated atomic accumulate
  const float e2 = (cb == 0) ? eb2[k] : 0.f;
  for (int t = tid; t < npb * 32; t += 256) {
    int pp = t >> 5, r = t & 31;
    int i = (qz + 4 * pp) * 32 + r;
    if (i < n) {
      float v = pb[pp][0][r] + pb[pp][1][r] + pb[pp][2][r] + pb[pp][3][r];
      atomicAdd(&y[list[kBn + i]], wlist[kBn + i] * (v + e2));
    }
  }
#undef ESTG
}

extern "C" void kernel_launch(void* const* d_in, const int* in_sizes, int n_in,
                              void* d_out, int out_size, void* d_ws, size_t ws_size,
                              hipStream_t stream) {
  const int* x      = (const int*)d_in[0];
  const int* sql    = (const int*)d_in[1];
  const float* semb = (const float*)d_in[2];
  const float* demb = (const float*)d_in[3];
  const float* gw1  = (const float*)d_in[4];
  const float* gb1  = (const float*)d_in[5];
  const float* gw2  = (const float*)d_in[6];
  const float* gb2  = (const float*)d_in[7];
  const float* ew1  = (const float*)d_in[8];
  const float* eb1  = (const float*)d_in[9];
  const float* ew2  = (const float*)d_in[10];
  const float* eb2  = (const float*)d_in[11];
  float* y = (float*)d_out;

  char* ws = (char*)d_ws;
  int* cnt            = (int*)(ws);                        // 64 B
  int* list           = (int*)(ws + 4096);                 // 256 KB
  float* wlist        = (float*)(ws + 266240);             // 256 KB
  float* glp          = (float*)(ws + 528384);             // 2 MB (8 slices)
  unsigned short* XE  = (unsigned short*)(ws + 2625536);   // 2.62 MB
  unsigned short* SH  = (unsigned short*)(ws + 5246976);   // 2.62 MB
  unsigned short* SL  = (unsigned short*)(ws + 7868416);   // 2.62 MB
  unsigned short* GWF = (unsigned short*)(ws + 10489856);  // 655 KB
  unsigned short* EWF = (unsigned short*)(ws + 11145216);  // 5.24 MB
  unsigned short* XEP = (unsigned short*)(ws + 16777216);  // 42 MB packed A

  prep_kernel<<<2097, 256, 0, stream>>>(x, sql, demb, semb, gw1, ew1,
                                        XE, SH, SL, GWF, EWF, y, cnt);
  gate_kernel<<<dim3(32, 8), 256, 0, stream>>>(SH, SL, GWF, gb1, gw2, glp);
  gate2_kernel<<<Bn / 256, 256, 0, stream>>>(glp, gb2, cnt, list, wlist);
  packloss_kernel<<<dim3(65, 16), 256, 0, stream>>>(XE, cnt, list, wlist, XEP, y);
  expert_kernel<<<dim3(4, 16, 4), 256, 0, stream>>>(XEP, EWF, eb1, ew2, eb2,
                                                    cnt, list, wlist, y);
}

// Round 9
// 72.019 us; speedup vs baseline: 2.9207x; 1.1399x over previous
//
#include <hip/hip_runtime.h>

#define Bn 4096
#define NF 20
#define NEMB 16
#define HIDN 512
#define KE 16
#define GIN 320
#define NKS 10   // K-steps of 32

typedef __attribute__((ext_vector_type(8))) short short8;
typedef __attribute__((ext_vector_type(4))) float f32x4;

__device__ __forceinline__ unsigned short f2bf(float f) {
  unsigned int u = __builtin_bit_cast(unsigned int, f);
  u += 0x7fff + ((u >> 16) & 1);
  return (unsigned short)(u >> 16);
}
__device__ __forceinline__ float bf2f(unsigned short h) {
  unsigned int u = ((unsigned int)h) << 16;
  return __builtin_bit_cast(float, u);
}

__device__ __forceinline__ void gload_lds16(const unsigned short* g, void* l) {
  __builtin_amdgcn_global_load_lds(
      (const __attribute__((address_space(1))) unsigned int*)g,
      (__attribute__((address_space(3))) unsigned int*)l, 16, 0, 0);
}

__device__ __forceinline__ void vwait(int n) {
  if (n >= 5) asm volatile("s_waitcnt vmcnt(5)" ::: "memory");
  else        asm volatile("s_waitcnt vmcnt(0)" ::: "memory");
  __builtin_amdgcn_sched_barrier(0);
}

// ---------------- prep: SH/SL gather-convert, GWF/EWF fragment weights ------
__global__ __launch_bounds__(256) void prep_kernel(
    const int* __restrict__ sql, const float* __restrict__ semb,
    const float* __restrict__ gw1, const float* __restrict__ ew1,
    unsigned short* __restrict__ SH, unsigned short* __restrict__ SL,
    unsigned short* __restrict__ GWF, unsigned short* __restrict__ EWF,
    float* __restrict__ y, int* __restrict__ cnt) {
  long long t = (long long)blockIdx.x * 256 + threadIdx.x;
  if (t < 81920) {
    int row = (int)(t / NF), f = (int)(t % NF);
    int idx = sql[row * NF + f];
    const float4* s = (const float4*)(semb + (size_t)idx * NEMB);
    float4 v[4] = {s[0], s[1], s[2], s[3]};
    const float* sf = (const float*)v;
    short8 h0, h1, l0, l1;
#pragma unroll
    for (int i = 0; i < 8; i++) {
      float a = sf[i];
      unsigned short hb = f2bf(a);
      h0[i] = (short)hb; l0[i] = (short)f2bf(a - bf2f(hb));
      a = sf[8 + i];
      hb = f2bf(a);
      h1[i] = (short)hb; l1[i] = (short)f2bf(a - bf2f(hb));
    }
    size_t o = (size_t)row * GIN + f * NEMB;
    *(short8*)(SH + o) = h0; *(short8*)(SH + o + 8) = h1;
    *(short8*)(SL + o) = l0; *(short8*)(SL + o + 8) = l1;
    return;
  }
  t -= 81920;
  if (t < 40960) {
    int s = (int)(t / 20480), r = (int)(t % 20480);
    int ks = r / 2048, r2 = r % 2048, nt = r2 / 64, l = r2 % 64;
    int k0 = ks * 32 + (l >> 4) * 8, n = nt * 16 + (l & 15);
    short8 o;
#pragma unroll
    for (int j = 0; j < 8; j++) {
      float w = gw1[(size_t)(k0 + j) * HIDN + n];
      unsigned short hb = f2bf(w);
      o[j] = (s == 0) ? (short)hb : (short)f2bf(w - bf2f(hb));
    }
    *(short8*)(GWF + ((((size_t)s * NKS + ks) * 32 + nt) * 64 + l) * 8) = o;
    return;
  }
  t -= 40960;
  if (t < 327680) {
    int e = (int)(t / 20480), r = (int)(t % 20480);
    int ks = r / 2048, r2 = r % 2048, nt = r2 / 64, l = r2 % 64;
    int k0 = ks * 32 + (l >> 4) * 8, n = nt * 16 + (l & 15);
    const float* W = ew1 + (size_t)e * GIN * HIDN;
    short8 o;
#pragma unroll
    for (int j = 0; j < 8; j++) o[j] = (short)f2bf(W[(size_t)(k0 + j) * HIDN + n]);
    *(short8*)(EWF + ((((size_t)e * NKS + ks) * 32 + nt) * 64 + l) * 8) = o;
    return;
  }
  t -= 327680;
  if (t < Bn + 1) y[t] = 0.f;
  else if (t < Bn + 1 + KE) cnt[t - (Bn + 1)] = 0;
}

// ---------------- gate: split-bf16 MFMA, ring-3 panels of 16 rows -----------
// grid (64 bands of 64, 8 colblocks of 64); 2 blocks/CU (78.8 KB LDS).
__global__ __launch_bounds__(256, 2) void gate_kernel(
    const unsigned short* __restrict__ SH, const unsigned short* __restrict__ SL,
    const unsigned short* __restrict__ GWF, const float* __restrict__ gb1,
    const float* __restrict__ gw2, float* __restrict__ glp) {
  __shared__ __align__(16) unsigned short ring[3][10240];  // 60 KB
  __shared__ float hs[64][68];                             // 17.4 KB
  const int tid = threadIdx.x, lane = tid & 63, wv = tid >> 6;
  const int band = blockIdx.x * 64, cb = blockIdx.y;
  const int ntg = cb * 4 + wv;

  // B fragments (hi+lo) in registers, bias
  short8 bh[NKS], bl[NKS];
#pragma unroll
  for (int ks = 0; ks < NKS; ks++) {
    bh[ks] = *(const short8*)(GWF + ((size_t)(ks * 32 + ntg)) * 512 + lane * 8);
    bl[ks] = *(const short8*)(GWF + ((size_t)((NKS + ks) * 32 + ntg)) * 512 + lane * 8);
  }
  const int cl = wv * 16 + (lane & 15);
  const float b1v = gb1[cb * 64 + cl];
  __builtin_amdgcn_sched_barrier(0);

#define GSTG(pi, slot)                                                        \
  {                                                                           \
    _Pragma("unroll") for (int i = 0; i < 5; i++) {                           \
      int c = wv * 5 + i;                                                     \
      int hl = c >= 10, kss = c - hl * 10;                                    \
      const unsigned short* s_ = (hl ? SL : SH) +                             \
          (size_t)(band + (pi) * 16 + (lane & 15)) * GIN + kss * 32 +         \
          (lane >> 4) * 8;                                                    \
      gload_lds16(s_, &ring[slot][c * 512 + lane * 8]);                       \
    }                                                                         \
  }

  GSTG(0, 0) GSTG(1, 1)
  __builtin_amdgcn_sched_barrier(0);

#pragma unroll
  for (int p = 0; p < 4; p++) {
    vwait(p < 3 ? 5 : 0);              // own chunks of panel p retired
    __builtin_amdgcn_s_barrier();      // all waves' chunks retired
    __builtin_amdgcn_sched_barrier(0);
    if (p + 2 < 4) GSTG(p + 2, (p + 2) % 3)
    __builtin_amdgcn_sched_barrier(0);
    const unsigned short* rb = ring[p % 3];
    f32x4 acc = {};
#pragma unroll
    for (int ks = 0; ks < NKS; ks++) {
      short8 ah = *(const short8*)&rb[ks * 512 + lane * 8];
      short8 al = *(const short8*)&rb[(NKS + ks) * 512 + lane * 8];
      acc = __builtin_amdgcn_mfma_f32_16x16x32_bf16(ah, bh[ks], acc, 0, 0, 0);
      acc = __builtin_amdgcn_mfma_f32_16x16x32_bf16(al, bh[ks], acc, 0, 0, 0);
      acc = __builtin_amdgcn_mfma_f32_16x16x32_bf16(ah, bl[ks], acc, 0, 0, 0);
    }
#pragma unroll
    for (int j = 0; j < 4; j++)
      hs[p * 16 + (lane >> 4) * 4 + j][cl] = fmaxf(acc[j] + b1v, 0.f);
  }
  __syncthreads();

  // logits epilogue; gw2 slice staged into ring[0] (reused)
  float (*g2s)[16] = (float(*)[16])&ring[0][0];
  ((float4*)g2s)[tid] = ((const float4*)(gw2 + (size_t)cb * 64 * KE))[tid];
  __syncthreads();
#pragma unroll
  for (int it = 0; it < 4; it++) {
    int row = it * 16 + (tid >> 4), q = tid & 15;
    float s = 0.f;
#pragma unroll 8
    for (int c = 0; c < 64; c++) s = fmaf(hs[row][c], g2s[c][q], s);
    glp[((size_t)cb * Bn + band + row) * KE + q] = s;
  }
#undef GSTG
}

// ---------------- gate2: sum 8 partials, softmax, top-2, bucket -------------
__global__ __launch_bounds__(256) void gate2_kernel(
    const float* __restrict__ glp, const float* __restrict__ gb2,
    int* __restrict__ cnt, int* __restrict__ list, float* __restrict__ wlist) {
  __shared__ int lcnt[KE];
  __shared__ int gbase[KE];
  const int tid = threadIdx.x;
  const int row = blockIdx.x * 256 + tid;
  if (tid < KE) lcnt[tid] = 0;
  __syncthreads();
  float lg[KE];
  {
    const float4* c = (const float4*)gb2;
#pragma unroll
    for (int u = 0; u < 4; u++) {
      float4 s = c[u];
      lg[u * 4 + 0] = s.x; lg[u * 4 + 1] = s.y;
      lg[u * 4 + 2] = s.z; lg[u * 4 + 3] = s.w;
    }
#pragma unroll
    for (int sl = 0; sl < 8; sl++) {
      const float4* a = (const float4*)(glp + ((size_t)sl * Bn + row) * KE);
#pragma unroll
      for (int u = 0; u < 4; u++) {
        float4 v = a[u];
        lg[u * 4 + 0] += v.x; lg[u * 4 + 1] += v.y;
        lg[u * 4 + 2] += v.z; lg[u * 4 + 3] += v.w;
      }
    }
  }
  float m = lg[0];
#pragma unroll
  for (int q = 1; q < KE; q++) m = fmaxf(m, lg[q]);
  float e[KE];
#pragma unroll
  for (int q = 0; q < KE; q++) e[q] = expf(lg[q] - m);
  int i1 = 0; float v1 = e[0];
#pragma unroll
  for (int q = 1; q < KE; q++) if (e[q] > v1) { v1 = e[q]; i1 = q; }
  int i2 = (i1 == 0) ? 1 : 0; float v2 = e[i2];
#pragma unroll
  for (int q = 0; q < KE; q++)
    if (q != i1 && e[q] > v2) { v2 = e[q]; i2 = q; }
  int o1 = atomicAdd(&lcnt[i1], 1);
  int o2 = atomicAdd(&lcnt[i2], 1);
  __syncthreads();
  if (tid < KE) gbase[tid] = atomicAdd(&cnt[tid], lcnt[tid]);
  __syncthreads();
  float den = v1 + v2;
  int s1 = gbase[i1] + o1;
  list[i1 * Bn + s1] = row; wlist[i1 * Bn + s1] = v1 / den;
  int s2 = gbase[i2] + o2;
  list[i2 * Bn + s2] = row; wlist[i2 * Bn + s2] = v2 / den;
}

// ---------------- pack (+loss): gather demb, convert, fragment-pack ---------
// grid (65, 16): jb<64 pack 64 rows of expert k; jb==64,k==0 computes loss.
__global__ __launch_bounds__(256) void packloss_kernel(
    const int* __restrict__ x, const float* __restrict__ demb,
    const int* __restrict__ cnt, const int* __restrict__ list,
    const float* __restrict__ wlist, unsigned short* __restrict__ XEP,
    float* __restrict__ out) {
  __shared__ float simp[KE][KE];
  __shared__ float fimp[KE];
  const int tid = threadIdx.x;
  const int jb = blockIdx.x, k = blockIdx.y;
  if (jb == 64) {
    if (k != 0) return;
    const int kk = tid >> 4, g = tid & 15;
    const int n = cnt[kk];
    float s = 0.f;
    for (int j = g; j < n; j += 16) s += wlist[kk * Bn + j];
    simp[kk][g] = s;
    __syncthreads();
    if (tid < KE) {
      float t = 0.f;
      for (int q = 0; q < KE; q++) t += simp[tid][q];
      fimp[tid] = t;
    }
    __syncthreads();
    if (tid == 0) {
      double mi = 0.0, ml = 0.0;
      for (int q = 0; q < KE; q++) { mi += fimp[q]; ml += (double)cnt[q]; }
      mi /= KE; ml /= KE;
      double vi = 0.0, vl = 0.0;
      for (int q = 0; q < KE; q++) {
        double di = fimp[q] - mi; vi += di * di;
        double dl = (double)cnt[q] - ml; vl += dl * dl;
      }
      vi /= KE; vl /= KE;
      out[Bn] = (float)(vi / (mi * mi + 1e-10) + vl / (ml * ml + 1e-10));
    }
    return;
  }
  const int n = cnt[k];
  if (jb * 64 >= n) return;
  unsigned short* reg = XEP + (size_t)k * 1310720;
#pragma unroll
  for (int it = 0; it < 5; it++) {
    int tt = it * 256 + tid;
    int i = jb * 64 + tt / NF, f = tt % NF;
    if (i < n) {
      int rid = list[k * Bn + i];
      int idx = x[rid * NF + f];
      const float4* s = (const float4*)(demb + (size_t)idx * NEMB);
      float4 v[4] = {s[0], s[1], s[2], s[3]};
      const float* sf = (const float*)v;
      short8 o0, o1;
#pragma unroll
      for (int e = 0; e < 8; e++) {
        o0[e] = (short)f2bf(sf[e]);
        o1[e] = (short)f2bf(sf[8 + e]);
      }
      int panel = i >> 5, mt = (i >> 4) & 1, lr = i & 15;
      int ks = f >> 1, ko0 = (f & 1) * 2;
      unsigned short* d =
          reg + (size_t)panel * 10240 + ks * 1024 + mt * 512 + ko0 * 128 + lr * 8;
      *(short8*)d = o0;
      *(short8*)(d + 128) = o1;
    }
  }
}

// ---------------- experts: ring-3 panel pipeline over packed A --------------
// grid (4 colblocks of 128, 16 experts, 8 row-eighths); 2 blocks/CU (68 KB).
__global__ __launch_bounds__(256, 2) void expert_kernel(
    const unsigned short* __restrict__ XEP, const unsigned short* __restrict__ EWF,
    const float* __restrict__ eb1, const float* __restrict__ ew2,
    const float* __restrict__ eb2, const int* __restrict__ cnt,
    const int* __restrict__ list, const float* __restrict__ wlist,
    float* __restrict__ y) {
  __shared__ __align__(16) unsigned short ring[3][10240];  // 60 KB
  __shared__ float pb[16][4][32];                          // 8 KB
  const int tid = threadIdx.x, lane = tid & 63, wv = tid >> 6;
  const int cb = blockIdx.x, k = blockIdx.y, qz = blockIdx.z;
  const int n = cnt[k];
  const int np = (n + 31) >> 5;
  const int npb = (np > qz) ? ((np - qz + 7) >> 3) : 0;
  if (npb == 0) return;
  const unsigned short* XEPk = XEP + (size_t)k * 1310720;
  const int kBn = k * Bn;

  float b1v[2], w2v[2];
#pragma unroll
  for (int nt = 0; nt < 2; nt++) {
    int colg = cb * 128 + (wv * 2 + nt) * 16 + (lane & 15);
    b1v[nt] = eb1[(size_t)k * HIDN + colg];
    w2v[nt] = ew2[(size_t)k * HIDN + colg];
  }
  short8 bb[2][NKS];
#pragma unroll
  for (int nt = 0; nt < 2; nt++)
#pragma unroll
    for (int ks = 0; ks < NKS; ks++)
      bb[nt][ks] = *(const short8*)(
          EWF + ((size_t)((k * NKS + ks) * 32 + cb * 8 + wv * 2 + nt)) * 512 +
          lane * 8);
  __builtin_amdgcn_sched_barrier(0);

#define ESTG(pi, slot)                                                        \
  {                                                                           \
    _Pragma("unroll") for (int i = 0; i < 5; i++) {                           \
      int c = wv * 5 + i;                                                     \
      gload_lds16(XEPk + (size_t)(pi) * 10240 + c * 512 + lane * 8,           \
                  &ring[slot][c * 512 + lane * 8]);                           \
    }                                                                         \
  }

  ESTG(qz, 0)
  if (npb > 1) ESTG(qz + 8, 1)
  __builtin_amdgcn_sched_barrier(0);

  for (int p = 0; p < npb; p++) {
    vwait((p + 1 < npb) ? 5 : 0);
    __builtin_amdgcn_s_barrier();
    __builtin_amdgcn_sched_barrier(0);
    if (p + 2 < npb) ESTG(qz + 8 * (p + 2), (p + 2) % 3)
    __builtin_amdgcn_sched_barrier(0);
    const unsigned short* rb = ring[p % 3];
    f32x4 acc[2][2] = {};
#pragma unroll
    for (int ks = 0; ks < NKS; ks++) {
      short8 a0 = *(const short8*)&rb[ks * 1024 + lane * 8];
      short8 a1 = *(const short8*)&rb[ks * 1024 + 512 + lane * 8];
      acc[0][0] = __builtin_amdgcn_mfma_f32_16x16x32_bf16(a0, bb[0][ks], acc[0][0], 0, 0, 0);
      acc[0][1] = __builtin_amdgcn_mfma_f32_16x16x32_bf16(a0, bb[1][ks], acc[0][1], 0, 0, 0);
      acc[1][0] = __builtin_amdgcn_mfma_f32_16x16x32_bf16(a1, bb[0][ks], acc[1][0], 0, 0, 0);
      acc[1][1] = __builtin_amdgcn_mfma_f32_16x16x32_bf16(a1, bb[1][ks], acc[1][1], 0, 0, 0);
    }
    float part[2][4];
#pragma unroll
    for (int mt = 0; mt < 2; mt++)
#pragma unroll
      for (int j = 0; j < 4; j++)
        part[mt][j] = fmaxf(acc[mt][0][j] + b1v[0], 0.f) * w2v[0] +
                      fmaxf(acc[mt][1][j] + b1v[1], 0.f) * w2v[1];
#pragma unroll
    for (int off = 8; off >= 1; off >>= 1)
#pragma unroll
      for (int mt = 0; mt < 2; mt++)
#pragma unroll
        for (int j = 0; j < 4; j++)
          part[mt][j] += __shfl_xor(part[mt][j], off);
    if ((lane & 15) == 0) {
#pragma unroll
      for (int mt = 0; mt < 2; mt++)
#pragma unroll
        for (int j = 0; j < 4; j++)
          pb[p][wv][mt * 16 + (lane >> 4) * 4 + j] = part[mt][j];
    }
  }
  __syncthreads();

  const float e2 = (cb == 0) ? eb2[k] : 0.f;
  for (int t = tid; t < npb * 32; t += 256) {
    int pp = t >> 5, r = t & 31;
    int i = (qz + 8 * pp) * 32 + r;
    if (i < n) {
      float v = pb[pp][0][r] + pb[pp][1][r] + pb[pp][2][r] + pb[pp][3][r];
      atomicAdd(&y[list[kBn + i]], wlist[kBn + i] * (v + e2));
    }
  }
#undef ESTG
}

extern "C" void kernel_launch(void* const* d_in, const int* in_sizes, int n_in,
                              void* d_out, int out_size, void* d_ws, size_t ws_size,
                              hipStream_t stream) {
  const int* x      = (const int*)d_in[0];
  const int* sql    = (const int*)d_in[1];
  const float* semb = (const float*)d_in[2];
  const float* demb = (const float*)d_in[3];
  const float* gw1  = (const float*)d_in[4];
  const float* gb1  = (const float*)d_in[5];
  const float* gw2  = (const float*)d_in[6];
  const float* gb2  = (const float*)d_in[7];
  const float* ew1  = (const float*)d_in[8];
  const float* eb1  = (const float*)d_in[9];
  const float* ew2  = (const float*)d_in[10];
  const float* eb2  = (const float*)d_in[11];
  float* y = (float*)d_out;

  char* ws = (char*)d_ws;
  int* cnt            = (int*)(ws);                        // 64 B
  int* list           = (int*)(ws + 4096);                 // 256 KB
  float* wlist        = (float*)(ws + 266240);             // 256 KB
  float* glp          = (float*)(ws + 528384);             // 2 MB (8 slices)
  unsigned short* SH  = (unsigned short*)(ws + 5246976);   // 2.62 MB
  unsigned short* SL  = (unsigned short*)(ws + 7868416);   // 2.62 MB
  unsigned short* GWF = (unsigned short*)(ws + 10489856);  // 655 KB
  unsigned short* EWF = (unsigned short*)(ws + 11145216);  // 5.24 MB
  unsigned short* XEP = (unsigned short*)(ws + 16777216);  // 42 MB packed A

  prep_kernel<<<1777, 256, 0, stream>>>(sql, semb, gw1, ew1,
                                        SH, SL, GWF, EWF, y, cnt);
  gate_kernel<<<dim3(64, 8), 256, 0, stream>>>(SH, SL, GWF, gb1, gw2, glp);
  gate2_kernel<<<Bn / 256, 256, 0, stream>>>(glp, gb2, cnt, list, wlist);
  packloss_kernel<<<dim3(65, 16), 256, 0, stream>>>(x, demb, cnt, list, wlist,
                                                    XEP, y);
  expert_kernel<<<dim3(4, 16, 8), 256, 0, stream>>>(XEP, EWF, eb1, ew2, eb2,
                                                    cnt, list, wlist, y);
}